// Round 18
// baseline (366.419 us; speedup 1.0000x reference)
//
#include <hip/hip_runtime.h>
#include <math.h>

#define NB 16
#define PP 1024
#define DD 64
#define MAX_ITER 10
#define RCH 16                 // rows per iter-block chunk
#define NCH (PP / RCH)         // 64 chunks per batch
#define NBLK (NB * NCH)        // 1024 iter blocks
#define CH (NB * PP)           // 16384

constexpr float EPSV    = 0.1f;
constexpr float SCALE_G = 20.0f;     // 2/eps
constexpr float LOG2E   = 1.44269504088896340736f;
constexpr float LOG_MU  = -6.93146156597137f;   // log(1/1024 + 1e-8)
constexpr float THRESHV = 0.1f;

typedef short bf16x8 __attribute__((ext_vector_type(8)));
typedef float f32x16 __attribute__((ext_vector_type(16)));

__device__ __forceinline__ unsigned short f2bf(float f) {
  unsigned int u = __float_as_uint(f);
  return (unsigned short)((u + 0x7FFFu + ((u >> 16) & 1u)) >> 16);   // RNE
}
__device__ __forceinline__ float bf2f(unsigned short h) {
  return __uint_as_float(((unsigned int)h) << 16);
}

// Packed-fragment addressing (validated r13).
__device__ __forceinline__ const bf16x8* frag(const unsigned short* pk, int g, int q, int l) {
  return (const bf16x8*)(pk + (((size_t)g * 4 + q) * 64 + l) * 8);
}

// ---------------------------------------------------------------------------
// Prep (validated r13): bf16 hi/lo split into packed fragments + norms.
// ---------------------------------------------------------------------------
__global__ __launch_bounds__(256) void prep_kernel(
    const float* __restrict__ x, const float* __restrict__ y,
    unsigned short* __restrict__ xhp, unsigned short* __restrict__ xlp,
    unsigned short* __restrict__ yhp, unsigned short* __restrict__ ylp,
    float* __restrict__ nxs, float* __restrict__ nys)
{
  const int sel = blockIdx.x >> 9;
  const int row = (blockIdx.x & 511) * 32 + (threadIdx.x >> 3);
  const int q   = threadIdx.x & 7;

  const float* src = sel ? y : x;
  unsigned short* H = sel ? yhp : xhp;
  unsigned short* L = sel ? ylp : xlp;
  float* N          = sel ? nys : nxs;

  const float* p = src + (size_t)row * DD + q * 8;
  float4 v0 = *(const float4*)(p);
  float4 v1 = *(const float4*)(p + 4);

  float f[8] = {v0.x, v0.y, v0.z, v0.w, v1.x, v1.y, v1.z, v1.w};
  float nrm = 0.f;
  unsigned short hb[8], lb[8];
  #pragma unroll
  for (int k = 0; k < 8; ++k) {
    nrm = fmaf(f[k], f[k], nrm);
    unsigned short h = f2bf(f[k]);
    float res = f[k] - bf2f(h);
    hb[k] = h; lb[k] = f2bf(res);
  }
  nrm += __shfl_xor(nrm, 1);
  nrm += __shfl_xor(nrm, 2);
  nrm += __shfl_xor(nrm, 4);
  if (q == 0) N[row] = 10.0f * nrm;

  uint4 ho, lo;
  ho.x = hb[0] | ((unsigned)hb[1] << 16); ho.y = hb[2] | ((unsigned)hb[3] << 16);
  ho.z = hb[4] | ((unsigned)hb[5] << 16); ho.w = hb[6] | ((unsigned)hb[7] << 16);
  lo.x = lb[0] | ((unsigned)lb[1] << 16); lo.y = lb[2] | ((unsigned)lb[3] << 16);
  lo.z = lb[4] | ((unsigned)lb[5] << 16); lo.w = lb[6] | ((unsigned)lb[7] << 16);

  const int grp  = row >> 5;
  const int lane = (row & 31) + 32 * (q & 1);
  const size_t dst = (((size_t)grp * 4 + (q >> 1)) * 64 + lane) * 8;
  *(uint4*)(H + dst) = ho;
  *(uint4*)(L + dst) = lo;
}

// ---------------------------------------------------------------------------
// Cs = nxs_i + nys_j - 20*<x_i,y_j> via split-bf16 MFMA (validated r13/r16).
// ---------------------------------------------------------------------------
__global__ __launch_bounds__(256) void compute_c_mfma(
    const unsigned short* __restrict__ xhp, const unsigned short* __restrict__ xlp,
    const float* __restrict__ nxs,
    const unsigned short* __restrict__ yhp, const unsigned short* __restrict__ ylp,
    const float* __restrict__ nys,
    float* __restrict__ Cs)
{
  const int n   = blockIdx.x & 15;
  const int ib  = (blockIdx.x >> 4) & 15;
  const int jb  = blockIdx.x >> 8;
  const int tid = threadIdx.x;
  const int l   = tid & 63;
  const int w   = tid >> 6;
  const int ih  = w & 1, jh = w >> 1;

  __shared__ float nxv[64];
  if (tid < 64) nxv[tid] = nxs[n * PP + ib * 64 + tid];
  __syncthreads();

  const int jg  = n * PP + jb * 64 + 32 * jh + (l & 31);
  const float nyv = nys[jg];

  const int gX = n * 32 + ib * 2 + ih;
  const int gY = n * 32 + jb * 2 + jh;

  f32x16 acc;
  #pragma unroll
  for (int z = 0; z < 16; ++z) acc[z] = 0.f;
  #pragma unroll
  for (int q = 0; q < 4; ++q) {
    bf16x8 Xh = *frag(xhp, gX, q, l);
    bf16x8 Xl = *frag(xlp, gX, q, l);
    bf16x8 Yh = *frag(yhp, gY, q, l);
    bf16x8 Yl = *frag(ylp, gY, q, l);
    acc = __builtin_amdgcn_mfma_f32_32x32x16_bf16(Xh, Yh, acc, 0, 0, 0);
    acc = __builtin_amdgcn_mfma_f32_32x32x16_bf16(Xh, Yl, acc, 0, 0, 0);
    acc = __builtin_amdgcn_mfma_f32_32x32x16_bf16(Xl, Yh, acc, 0, 0, 0);
  }

  const int irb  = 32 * ih + 4 * (l >> 5);
  const int jcol = jb * 64 + 32 * jh + (l & 31);
  #pragma unroll
  for (int r = 0; r < 16; ++r) {
    const int irel = irb + (r & 3) + 8 * (r >> 2);
    const size_t off = ((size_t)(n * PP + ib * 64 + irel)) * PP + jcol;
    Cs[off] = nxv[irel] + nyv - SCALE_G * acc[r];
  }
}

// ---------------------------------------------------------------------------
// Fused iteration v2: Cs read EXACTLY ONCE. Row phase as r17 (wave-contiguous
// stream into tv regs). Col phase recovered from tv algebraically:
//   a_i - Cs = a_i - b_j + tv  (tv = b_j - Cs)
// Per-thread 4-row col partials (pure VALU) -> LDS [4 waves][1024] -> 4-way
// merge -> global pm/ps (same semantics as r16/r17). No col-phase Cs loads.
// ---------------------------------------------------------------------------
__global__ __launch_bounds__(256, 4) void iter_fused(
    const float* __restrict__ Cs, float* __restrict__ aG, const float* __restrict__ bG,
    float* __restrict__ pm, float* __restrict__ ps, float* __restrict__ errBlk,
    const int* __restrict__ doneFlags, int it)
{
  if (it > 0 && doneFlags[it - 1]) return;   // frozen: a,b,partials untouched

  const int n   = blockIdx.x & 15;
  const int rc  = blockIdx.x >> 4;
  const int tid = threadIdx.x;
  const int l   = tid & 63;
  const int wv  = tid >> 6;

  __shared__ float bb[PP];          // 4 KB
  __shared__ float pmL[4][PP];      // 16 KB
  __shared__ float psL[4][PP];      // 16 KB
  __shared__ float aArr[RCH];
  __shared__ float dsum[RCH];

  if (it == 0) {
    *(float4*)&bb[tid * 4] = make_float4(0.f, 0.f, 0.f, 0.f);
  } else {
    *(float4*)&bb[tid * 4] = *(const float4*)(bG + n * PP + tid * 4);
  }
  __syncthreads();

  // ---- row phase: wave wv streams rows 4wv..4wv+3 (16 KB contiguous) ----
  const int rbase = rc * RCH + 4 * wv;
  const float* cbase = Cs + ((size_t)(n * PP + rbase)) * PP;

  float4 bbv[4];
  #pragma unroll
  for (int s = 0; s < 4; ++s) bbv[s] = *(const float4*)&bb[s * 256 + l * 4];

  float4 tv[16];
  #pragma unroll
  for (int t = 0; t < 16; ++t) {
    const int r = t >> 2, s = t & 3;
    float4 c4 = *(const float4*)(cbase + (size_t)r * PP + s * 256 + l * 4);
    tv[t] = make_float4(bbv[s].x - c4.x, bbv[s].y - c4.y,
                        bbv[s].z - c4.z, bbv[s].w - c4.w);
  }

  float m0 = -INFINITY, m1 = -INFINITY, m2 = -INFINITY, m3 = -INFINITY;
  #pragma unroll
  for (int s = 0; s < 4; ++s) {
    m0 = fmaxf(m0, fmaxf(fmaxf(tv[s].x, tv[s].y), fmaxf(tv[s].z, tv[s].w)));
    m1 = fmaxf(m1, fmaxf(fmaxf(tv[4+s].x, tv[4+s].y), fmaxf(tv[4+s].z, tv[4+s].w)));
    m2 = fmaxf(m2, fmaxf(fmaxf(tv[8+s].x, tv[8+s].y), fmaxf(tv[8+s].z, tv[8+s].w)));
    m3 = fmaxf(m3, fmaxf(fmaxf(tv[12+s].x, tv[12+s].y), fmaxf(tv[12+s].z, tv[12+s].w)));
  }
  #pragma unroll
  for (int mask = 32; mask; mask >>= 1) {
    m0 = fmaxf(m0, __shfl_xor(m0, mask));
    m1 = fmaxf(m1, __shfl_xor(m1, mask));
    m2 = fmaxf(m2, __shfl_xor(m2, mask));
    m3 = fmaxf(m3, __shfl_xor(m3, mask));
  }

  float s0 = 0.f, s1 = 0.f, s2 = 0.f, s3 = 0.f;
  #pragma unroll
  for (int s = 0; s < 4; ++s) {
    s0 += exp2f((tv[s].x - m0) * LOG2E) + exp2f((tv[s].y - m0) * LOG2E)
        + exp2f((tv[s].z - m0) * LOG2E) + exp2f((tv[s].w - m0) * LOG2E);
    s1 += exp2f((tv[4+s].x - m1) * LOG2E) + exp2f((tv[4+s].y - m1) * LOG2E)
        + exp2f((tv[4+s].z - m1) * LOG2E) + exp2f((tv[4+s].w - m1) * LOG2E);
    s2 += exp2f((tv[8+s].x - m2) * LOG2E) + exp2f((tv[8+s].y - m2) * LOG2E)
        + exp2f((tv[8+s].z - m2) * LOG2E) + exp2f((tv[8+s].w - m2) * LOG2E);
    s3 += exp2f((tv[12+s].x - m3) * LOG2E) + exp2f((tv[12+s].y - m3) * LOG2E)
        + exp2f((tv[12+s].z - m3) * LOG2E) + exp2f((tv[12+s].w - m3) * LOG2E);
  }
  #pragma unroll
  for (int mask = 32; mask; mask >>= 1) {
    s0 += __shfl_xor(s0, mask);
    s1 += __shfl_xor(s1, mask);
    s2 += __shfl_xor(s2, mask);
    s3 += __shfl_xor(s3, mask);
  }

  if (l == 0) {
    float mg[4] = {m0, m1, m2, m3};
    float sg[4] = {s0, s1, s2, s3};
    #pragma unroll
    for (int g = 0; g < 4; ++g) {
      const int row = n * PP + rbase + g;
      float aOld = (it == 0) ? 0.f : aG[row];
      float an = LOG_MU - (mg[g] + logf(sg[g]));
      aG[row] = an;
      aArr[4 * wv + g] = an;
      dsum[4 * wv + g] = fabsf(an - aOld);
    }
  }
  __syncthreads();
  if (tid == 0) {
    float e = 0.f;
    #pragma unroll
    for (int r = 0; r < RCH; ++r) e += dsum[r];
    errBlk[blockIdx.x] = e;
  }

  // ---- col phase from registers: score = a_r + tv - b_c ----
  float a4[4];
  #pragma unroll
  for (int g = 0; g < 4; ++g) a4[g] = aArr[4 * wv + g];

  #pragma unroll
  for (int s = 0; s < 4; ++s) {
    float4 q0 = tv[s], q1 = tv[4 + s], q2 = tv[8 + s], q3 = tv[12 + s];
    float4 b4 = bbv[s];
    // scores per row r, componentwise: a4[r] - b + q_r
    float4 c0 = make_float4(a4[0] - b4.x + q0.x, a4[0] - b4.y + q0.y,
                            a4[0] - b4.z + q0.z, a4[0] - b4.w + q0.w);
    float4 c1 = make_float4(a4[1] - b4.x + q1.x, a4[1] - b4.y + q1.y,
                            a4[1] - b4.z + q1.z, a4[1] - b4.w + q1.w);
    float4 c2 = make_float4(a4[2] - b4.x + q2.x, a4[2] - b4.y + q2.y,
                            a4[2] - b4.z + q2.z, a4[2] - b4.w + q2.w);
    float4 c3 = make_float4(a4[3] - b4.x + q3.x, a4[3] - b4.y + q3.y,
                            a4[3] - b4.z + q3.z, a4[3] - b4.w + q3.w);
    float4 mm = make_float4(fmaxf(fmaxf(c0.x, c1.x), fmaxf(c2.x, c3.x)),
                            fmaxf(fmaxf(c0.y, c1.y), fmaxf(c2.y, c3.y)),
                            fmaxf(fmaxf(c0.z, c1.z), fmaxf(c2.z, c3.z)),
                            fmaxf(fmaxf(c0.w, c1.w), fmaxf(c2.w, c3.w)));
    float4 ss;
    ss.x = exp2f((c0.x - mm.x) * LOG2E) + exp2f((c1.x - mm.x) * LOG2E)
         + exp2f((c2.x - mm.x) * LOG2E) + exp2f((c3.x - mm.x) * LOG2E);
    ss.y = exp2f((c0.y - mm.y) * LOG2E) + exp2f((c1.y - mm.y) * LOG2E)
         + exp2f((c2.y - mm.y) * LOG2E) + exp2f((c3.y - mm.y) * LOG2E);
    ss.z = exp2f((c0.z - mm.z) * LOG2E) + exp2f((c1.z - mm.z) * LOG2E)
         + exp2f((c2.z - mm.z) * LOG2E) + exp2f((c3.z - mm.z) * LOG2E);
    ss.w = exp2f((c0.w - mm.w) * LOG2E) + exp2f((c1.w - mm.w) * LOG2E)
         + exp2f((c2.w - mm.w) * LOG2E) + exp2f((c3.w - mm.w) * LOG2E);
    *(float4*)&pmL[wv][s * 256 + l * 4] = mm;
    *(float4*)&psL[wv][s * 256 + l * 4] = ss;
  }
  __syncthreads();

  // ---- 4-way merge across waves; thread tid owns cols tid*4..+3 ----
  {
    const int c0i = tid * 4;
    float4 M0 = *(const float4*)&pmL[0][c0i];
    float4 M1 = *(const float4*)&pmL[1][c0i];
    float4 M2 = *(const float4*)&pmL[2][c0i];
    float4 M3 = *(const float4*)&pmL[3][c0i];
    float4 S0 = *(const float4*)&psL[0][c0i];
    float4 S1 = *(const float4*)&psL[1][c0i];
    float4 S2 = *(const float4*)&psL[2][c0i];
    float4 S3 = *(const float4*)&psL[3][c0i];
    float4 MM, SS;
    MM.x = fmaxf(fmaxf(M0.x, M1.x), fmaxf(M2.x, M3.x));
    MM.y = fmaxf(fmaxf(M0.y, M1.y), fmaxf(M2.y, M3.y));
    MM.z = fmaxf(fmaxf(M0.z, M1.z), fmaxf(M2.z, M3.z));
    MM.w = fmaxf(fmaxf(M0.w, M1.w), fmaxf(M2.w, M3.w));
    SS.x = S0.x * exp2f((M0.x - MM.x) * LOG2E) + S1.x * exp2f((M1.x - MM.x) * LOG2E)
         + S2.x * exp2f((M2.x - MM.x) * LOG2E) + S3.x * exp2f((M3.x - MM.x) * LOG2E);
    SS.y = S0.y * exp2f((M0.y - MM.y) * LOG2E) + S1.y * exp2f((M1.y - MM.y) * LOG2E)
         + S2.y * exp2f((M2.y - MM.y) * LOG2E) + S3.y * exp2f((M3.y - MM.y) * LOG2E);
    SS.z = S0.z * exp2f((M0.z - MM.z) * LOG2E) + S1.z * exp2f((M1.z - MM.z) * LOG2E)
         + S2.z * exp2f((M2.z - MM.z) * LOG2E) + S3.z * exp2f((M3.z - MM.z) * LOG2E);
    SS.w = S0.w * exp2f((M0.w - MM.w) * LOG2E) + S1.w * exp2f((M1.w - MM.w) * LOG2E)
         + S2.w * exp2f((M2.w - MM.w) * LOG2E) + S3.w * exp2f((M3.w - MM.w) * LOG2E);
    size_t off = ((size_t)(n * NCH + rc)) * PP + c0i;
    *(float4*)(pm + off) = MM;
    *(float4*)(ps + off) = SS;
  }
}

// ---------------------------------------------------------------------------
// Combine partials -> b; block 0 reduces errBlk -> doneFlags[it]. (r16 PROVEN)
// ---------------------------------------------------------------------------
__global__ __launch_bounds__(256) void v_combine(
    const float* __restrict__ pm, const float* __restrict__ ps,
    float* __restrict__ bG, const float* __restrict__ errBlk,
    int* __restrict__ doneFlags, int it)
{
  if (it > 0 && doneFlags[it - 1]) {
    if (blockIdx.x == 0 && threadIdx.x == 0) doneFlags[it] = 1;
    return;
  }
  const int col = blockIdx.x * 256 + threadIdx.x;   // 0..16383
  const int n = col >> 10, j = col & (PP - 1);
  const float* pmn = pm + (size_t)n * NCH * PP + j;
  const float* psn = ps + (size_t)n * NCH * PP + j;

  float m = -INFINITY, s = 0.f;
  #pragma unroll 8
  for (int c = 0; c < NCH; ++c) {
    float mc = pmn[(size_t)c * PP];
    float sc = psn[(size_t)c * PP];
    float mn = fmaxf(m, mc);
    s = fmaf(s, exp2f((m - mn) * LOG2E), sc * exp2f((mc - mn) * LOG2E));
    m = mn;
  }
  bG[col] = LOG_MU - (m + logf(s));

  if (blockIdx.x == 0) {
    __shared__ float red[4];
    float loc = 0.f;
    for (int t = threadIdx.x; t < NBLK; t += 256) loc += errBlk[t];
    #pragma unroll
    for (int off = 32; off > 0; off >>= 1) loc += __shfl_xor(loc, off);
    if ((threadIdx.x & 63) == 0) red[threadIdx.x >> 6] = loc;
    __syncthreads();
    if (threadIdx.x == 0) {
      float tot = red[0] + red[1] + red[2] + red[3];
      float err = tot * (EPSV / (float)NB);
      doneFlags[it] = (err < THRESHV) ? 1 : 0;
    }
  }
}

// ---------------------------------------------------------------------------
// pi_ij = exp((a_i - nxs_i) + (b_j - nys_j) + 20*<x_i,y_j>). (r16 PROVEN)
// ---------------------------------------------------------------------------
__global__ __launch_bounds__(256) void pi_mfma(
    const unsigned short* __restrict__ xhp, const unsigned short* __restrict__ xlp,
    const unsigned short* __restrict__ yhp, const unsigned short* __restrict__ ylp,
    const float* __restrict__ aG, const float* __restrict__ bG,
    const float* __restrict__ nxs, const float* __restrict__ nys,
    float* __restrict__ pi)
{
  const int n   = blockIdx.x & 15;
  const int ib  = (blockIdx.x >> 4) & 15;
  const int jb  = blockIdx.x >> 8;
  const int tid = threadIdx.x;
  const int l   = tid & 63;
  const int w   = tid >> 6;
  const int ih  = w & 1, jh = w >> 1;

  __shared__ float atv[64];
  if (tid < 64) {
    int gi = n * PP + ib * 64 + tid;
    atv[tid] = aG[gi] - nxs[gi];
  }
  __syncthreads();

  const int jg  = n * PP + jb * 64 + 32 * jh + (l & 31);
  const float btv = bG[jg] - nys[jg];

  const int gX = n * 32 + ib * 2 + ih;
  const int gY = n * 32 + jb * 2 + jh;

  f32x16 acc;
  #pragma unroll
  for (int z = 0; z < 16; ++z) acc[z] = 0.f;
  #pragma unroll
  for (int q = 0; q < 4; ++q) {
    bf16x8 Xh = *frag(xhp, gX, q, l);
    bf16x8 Xl = *frag(xlp, gX, q, l);
    bf16x8 Yh = *frag(yhp, gY, q, l);
    bf16x8 Yl = *frag(ylp, gY, q, l);
    acc = __builtin_amdgcn_mfma_f32_32x32x16_bf16(Xh, Yh, acc, 0, 0, 0);
    acc = __builtin_amdgcn_mfma_f32_32x32x16_bf16(Xh, Yl, acc, 0, 0, 0);
    acc = __builtin_amdgcn_mfma_f32_32x32x16_bf16(Xl, Yh, acc, 0, 0, 0);
  }

  const int irb  = 32 * ih + 4 * (l >> 5);
  const int jcol = jb * 64 + 32 * jh + (l & 31);
  #pragma unroll
  for (int r = 0; r < 16; ++r) {
    const int irel = irb + (r & 3) + 8 * (r >> 2);
    const size_t off = ((size_t)(n * PP + ib * 64 + irel)) * PP + jcol;
    pi[off] = exp2f((atv[irel] + btv + SCALE_G * acc[r]) * LOG2E);
  }
}

extern "C" void kernel_launch(void* const* d_in, const int* in_sizes, int n_in,
                              void* d_out, int out_size, void* d_ws, size_t ws_size,
                              hipStream_t stream)
{
  const float* y = (const float*)d_in[0];   // setup_inputs order: y first
  const float* x = (const float*)d_in[1];

  float* Cs = (float*)d_out;                 // Cs during iters; pi at the end

  // ws: first 8 MB is a UNION — packed bf16 frags alias pm/ps (r16 PROVEN).
  const size_t NE = (size_t)NB * PP * DD;
  unsigned short* xhp = (unsigned short*)d_ws;
  unsigned short* xlp = xhp + NE;
  unsigned short* yhp = xlp + NE;
  unsigned short* ylp = yhp + NE;
  float* pm = (float*)d_ws;                  // 4 MB
  float* ps = pm + (size_t)NB * NCH * PP;    // 4 MB

  float* tail   = (float*)((char*)d_ws + 4 * NE * sizeof(unsigned short)); // +8 MB
  float* nxs    = tail;
  float* nys    = nxs + CH;
  float* aG     = nys + CH;
  float* bG     = aG + CH;
  float* errBlk = bG + CH;
  int*   doneFl = (int*)(errBlk + NBLK);

  prep_kernel<<<1024, 256, 0, stream>>>(x, y, xhp, xlp, yhp, ylp, nxs, nys);
  compute_c_mfma<<<4096, 256, 0, stream>>>(xhp, xlp, nxs, yhp, ylp, nys, Cs);
  for (int it = 0; it < MAX_ITER; ++it) {
    iter_fused<<<NBLK, 256, 0, stream>>>(Cs, aG, bG, pm, ps, errBlk, doneFl, it);
    v_combine<<<NB * PP / 256, 256, 0, stream>>>(pm, ps, bG, errBlk, doneFl, it);
  }
  // regenerate packed frags (pm/ps clobbered them); idempotent
  prep_kernel<<<1024, 256, 0, stream>>>(x, y, xhp, xlp, yhp, ylp, nxs, nys);
  pi_mfma<<<4096, 256, 0, stream>>>(xhp, xlp, yhp, ylp, aG, bG, nxs, nys, Cs);
}